// Round 1
// baseline (1216.144 us; speedup 1.0000x reference)
//
#include <hip/hip_runtime.h>

typedef unsigned short u16;
typedef __bf16 bf16x8 __attribute__((ext_vector_type(8)));
typedef float f32x4 __attribute__((ext_vector_type(4)));

static __device__ __forceinline__ f32x4 mfma16(bf16x8 a, bf16x8 b, f32x4 c) {
  return __builtin_amdgcn_mfma_f32_16x16x32_bf16(a, b, c, 0, 0, 0);
}

static __device__ __forceinline__ u16 f2bf(float f) {
  union { float f; unsigned u; } v; v.f = f;
  unsigned r = v.u + 0x7fffu + ((v.u >> 16) & 1u);
  return (u16)(r >> 16);
}

// ---------------- mask element-size probe ----------------
// np bool_ (1B) vs int32 (4B): if int32 with 0/1 values, all bytes at
// offset%4!=0 are zero. P(false positive with random byte mask) ~ 2^-192.
__global__ void k_flag(const unsigned char* __restrict__ m, int* flag) {
  int t = threadIdx.x;  // 64 threads
  unsigned v = (unsigned)m[4*t+1] | (unsigned)m[4*t+2] | (unsigned)m[4*t+3];
  unsigned long long any = __ballot(v != 0);
  if (t == 0) *flag = (any == 0ull) ? 1 : 0;
}

// ---------------- weight transpose+convert: W[d][e] -> Wt[e][d] bf16 ----------------
__global__ __launch_bounds__(256) void k_wtr(const float* __restrict__ Wq,
                                             const float* __restrict__ Wk,
                                             const float* __restrict__ Wv,
                                             u16* __restrict__ Wt) {
  int m = blockIdx.z;
  const float* src = (m < 12) ? (Wq + (size_t)m * 65536)
                   : (m < 24) ? (Wk + (size_t)(m - 12) * 65536)
                              : (Wv + (size_t)(m - 24) * 65536);
  u16* dst = Wt + (size_t)m * 65536;
  __shared__ float T[64][65];
  int t = threadIdx.x;
  int d0 = blockIdx.x * 64, e0 = blockIdx.y * 64;
  for (int it = 0; it < 16; ++it) {
    int idx = it * 256 + t; int r = idx >> 6, c = idx & 63;
    T[r][c] = src[(size_t)(d0 + r) * 256 + e0 + c];
  }
  __syncthreads();
  for (int it = 0; it < 16; ++it) {
    int idx = it * 256 + t; int r = idx >> 6, c = idx & 63;
    dst[(size_t)(e0 + r) * 256 + d0 + c] = f2bf(T[c][r]);
  }
}

// ---------------- fp32 -> bf16 convert (+ optional fp32 copy) ----------------
__global__ __launch_bounds__(256) void k_cvt(const float* __restrict__ src,
                                             u16* __restrict__ db,
                                             float* dstf, long n) {
  long i = ((long)blockIdx.x * 256 + threadIdx.x) * 4;
  if (i >= n) return;
  float4 v = *(const float4*)(src + i);
  union { u16 u[4]; uint2 q; } o;
  o.u[0] = f2bf(v.x); o.u[1] = f2bf(v.y); o.u[2] = f2bf(v.z); o.u[3] = f2bf(v.w);
  *(uint2*)(db + i) = o.q;
  if (dstf) *(float4*)(dstf + i) = v;
}

// ---------------- fused 3-linear chain ----------------
// MODE 0: out[row][e] = chain(X)        (row-major [M,256] bf16)
// MODE 1: out = V^T per batch: Vt[b][e][row%Nk]  (computed as W^T @ X^T by
//         swapping MFMA operands; identical LDS access pattern)
template<int MODE>
__global__ __launch_bounds__(256, 2) void k_gemm3(const u16* __restrict__ X,
                                                  const u16* __restrict__ Wt,
                                                  const float* __restrict__ bias,
                                                  u16* __restrict__ out, int Nk) {
  __shared__ __align__(16) u16 Xs[64][264];   // activation rows (+pad)
  __shared__ __align__(16) u16 Ws[256][40];   // Wt rows e x 32-k chunk (+pad)
  int t = threadIdx.x, lane = t & 63, w = t >> 6, g = lane >> 4, li = lane & 15;
  long row0 = (long)blockIdx.x * 64;

  for (int it = 0; it < 8; ++it) {
    int c = it * 256 + t, r = c >> 5, k8 = (c & 31) << 3;
    *(uint4*)&Xs[r][k8] = *(const uint4*)&X[(row0 + r) * 256 + k8];
  }

  for (int j = 0; j < 3; ++j) {
    f32x4 acc[4][4];
#pragma unroll
    for (int i = 0; i < 4; ++i)
#pragma unroll
      for (int jj = 0; jj < 4; ++jj) acc[i][jj] = (f32x4){0.f, 0.f, 0.f, 0.f};
    const u16* Wj = Wt + j * 65536;
    for (int kk = 0; kk < 8; ++kk) {
#pragma unroll
      for (int it = 0; it < 4; ++it) {
        int c = it * 256 + t, n = c >> 2, p = c & 3;
        *(uint4*)&Ws[n][p << 3] = *(const uint4*)&Wj[n * 256 + kk * 32 + (p << 3)];
      }
      __syncthreads();
      bf16x8 xf[4], wf[4];
#pragma unroll
      for (int f = 0; f < 4; ++f) xf[f] = *(const bf16x8*)&Xs[f * 16 + li][kk * 32 + g * 8];
#pragma unroll
      for (int f = 0; f < 4; ++f) wf[f] = *(const bf16x8*)&Ws[w * 64 + f * 16 + li][g * 8];
#pragma unroll
      for (int i = 0; i < 4; ++i)
#pragma unroll
        for (int jj = 0; jj < 4; ++jj)
          acc[i][jj] = (MODE == 0) ? mfma16(xf[i], wf[jj], acc[i][jj])
                                   : mfma16(wf[i], xf[jj], acc[i][jj]);
      __syncthreads();
    }
    if (j < 2) {
#pragma unroll
      for (int i = 0; i < 4; ++i)
#pragma unroll
        for (int jj = 0; jj < 4; ++jj)
#pragma unroll
          for (int r = 0; r < 4; ++r) {
            int R, C;
            if (MODE == 0) { R = i * 16 + g * 4 + r; C = w * 64 + jj * 16 + li; }
            else           { R = jj * 16 + li;       C = w * 64 + i * 16 + g * 4 + r; }
            Xs[R][C] = f2bf(acc[i][jj][r] + bias[j * 256 + C]);
          }
      __syncthreads();
    } else {
      if (MODE == 0) {
#pragma unroll
        for (int i = 0; i < 4; ++i)
#pragma unroll
          for (int jj = 0; jj < 4; ++jj)
#pragma unroll
            for (int r = 0; r < 4; ++r) {
              int R = i * 16 + g * 4 + r, C = w * 64 + jj * 16 + li;
              out[(row0 + R) * 256 + C] = f2bf(acc[i][jj][r] + bias[512 + C]);
            }
      } else {
        long b = row0 / Nk, rb = row0 - b * Nk;
#pragma unroll
        for (int i = 0; i < 4; ++i)
#pragma unroll
          for (int jj = 0; jj < 4; ++jj)
#pragma unroll
            for (int r = 0; r < 4; ++r) {
              int e = w * 64 + i * 16 + g * 4 + r, xr = jj * 16 + li;
              out[(b * 256 + e) * (long)Nk + rb + xr] = f2bf(acc[i][jj][r] + bias[512 + e]);
            }
      }
    }
  }
}

// ---------------- flash attention + fused LayerNorm/residual ----------------
__global__ __launch_bounds__(256, 1) void k_attn(
    const u16* __restrict__ Qb, const u16* __restrict__ Kb, const u16* __restrict__ Vt,
    const void* __restrict__ mask, const int* __restrict__ flagp,
    const float* __restrict__ gamma, const float* __restrict__ beta,
    float* xres, u16* xbout,
    const float* __restrict__ future, float* __restrict__ dout, int last, int Nk) {
  __shared__ __align__(16) u16 Qs[64][264];
  __shared__ __align__(16) u16 Ks[32][264];
  __shared__ __align__(16) u16 Vs[256][40];
  __shared__ __align__(16) unsigned char Msk[64][32];
  __shared__ __align__(16) u16 Ps[4][16][40];
  __shared__ float gs[256], bs[256];

  int t = threadIdx.x, lane = t & 63, w = t >> 6, g = lane >> 4, li = lane & 15;
  int b = blockIdx.x >> 4, q0 = (blockIdx.x & 15) << 6;
  int flag = *flagp;
  gs[t] = gamma[t]; bs[t] = beta[t];

  const u16* Qbase = Qb + ((long)b * 1024 + q0) * 256;
  for (int it = 0; it < 8; ++it) {
    int c = it * 256 + t, r = c >> 5, k8 = (c & 31) << 3;
    *(uint4*)&Qs[r][k8] = *(const uint4*)&Qbase[(long)r * 256 + k8];
  }

  f32x4 O[16];
#pragma unroll
  for (int i = 0; i < 16; ++i) O[i] = (f32x4){0.f, 0.f, 0.f, 0.f};
  float m_i[4], l_i[4];
#pragma unroll
  for (int r = 0; r < 4; ++r) { m_i[r] = -1e30f; l_i[r] = 0.f; }

  const u16* Kbase0 = Kb + (long)b * Nk * 256;
  const u16* Vbase0 = Vt + (long)b * 256 * (long)Nk;
  int iters = Nk >> 5;
  for (int ki = 0; ki < iters; ++ki) {
    int kb = ki * 32;
    __syncthreads();
#pragma unroll
    for (int it = 0; it < 4; ++it) {
      int c = it * 256 + t, r = c >> 5, k8 = (c & 31) << 3;
      *(uint4*)&Ks[r][k8] = *(const uint4*)&Kbase0[(long)(kb + r) * 256 + k8];
    }
#pragma unroll
    for (int it = 0; it < 4; ++it) {
      int c = it * 256 + t, d = c >> 2, p = (c & 3) << 3;
      *(uint4*)&Vs[d][p] = *(const uint4*)&Vbase0[(long)d * Nk + kb + p];
    }
    if (flag) {
      const int* mi = (const int*)mask + ((long)b * 1024 + q0) * Nk + kb;
#pragma unroll
      for (int it = 0; it < 2; ++it) {
        int c = it * 256 + t, q = c >> 3, k4 = (c & 7) << 2;
        int4 v = *(const int4*)&mi[(long)q * Nk + k4];
        Msk[q][k4]     = (unsigned char)(v.x != 0);
        Msk[q][k4 + 1] = (unsigned char)(v.y != 0);
        Msk[q][k4 + 2] = (unsigned char)(v.z != 0);
        Msk[q][k4 + 3] = (unsigned char)(v.w != 0);
      }
    } else {
      const unsigned char* mu = (const unsigned char*)mask + ((long)b * 1024 + q0) * Nk + kb;
      int q = t >> 2, k8 = (t & 3) << 3;
      *(uint2*)&Msk[q][k8] = *(const uint2*)&mu[(long)q * Nk + k8];
    }
    __syncthreads();

    f32x4 s0 = (f32x4){0.f, 0.f, 0.f, 0.f}, s1 = (f32x4){0.f, 0.f, 0.f, 0.f};
#pragma unroll
    for (int kc = 0; kc < 8; ++kc) {
      bf16x8 a  = *(const bf16x8*)&Qs[w * 16 + li][kc * 32 + g * 8];
      bf16x8 k0 = *(const bf16x8*)&Ks[li][kc * 32 + g * 8];
      bf16x8 k1 = *(const bf16x8*)&Ks[16 + li][kc * 32 + g * 8];
      s0 = mfma16(a, k0, s0);
      s1 = mfma16(a, k1, s1);
    }

    float al[4], p0[4], p1[4];
#pragma unroll
    for (int r = 0; r < 4; ++r) {
      int q = w * 16 + g * 4 + r;
      float v0 = s0[r] * 0.0625f, v1 = s1[r] * 0.0625f;
      bool k0m = Msk[q][li] != 0, k1m = Msk[q][16 + li] != 0;
      v0 = k0m ? -1e30f : v0;
      v1 = k1m ? -1e30f : v1;
      float mx = fmaxf(v0, v1);
      mx = fmaxf(mx, __shfl_xor(mx, 1));
      mx = fmaxf(mx, __shfl_xor(mx, 2));
      mx = fmaxf(mx, __shfl_xor(mx, 4));
      mx = fmaxf(mx, __shfl_xor(mx, 8));
      float mn = fmaxf(m_i[r], mx);
      float a_ = __expf(m_i[r] - mn);
      float e0 = k0m ? 0.f : __expf(v0 - mn);
      float e1 = k1m ? 0.f : __expf(v1 - mn);
      float rs = e0 + e1;
      rs += __shfl_xor(rs, 1); rs += __shfl_xor(rs, 2);
      rs += __shfl_xor(rs, 4); rs += __shfl_xor(rs, 8);
      l_i[r] = l_i[r] * a_ + rs; m_i[r] = mn;
      al[r] = a_; p0[r] = e0; p1[r] = e1;
    }
#pragma unroll
    for (int df = 0; df < 16; ++df) {
      O[df][0] *= al[0]; O[df][1] *= al[1]; O[df][2] *= al[2]; O[df][3] *= al[3];
    }
#pragma unroll
    for (int r = 0; r < 4; ++r) {
      Ps[w][g * 4 + r][li]      = f2bf(p0[r]);
      Ps[w][g * 4 + r][16 + li] = f2bf(p1[r]);
    }
    bf16x8 pa = *(const bf16x8*)&Ps[w][li][g * 8];
#pragma unroll
    for (int df = 0; df < 16; ++df) {
      bf16x8 bv = *(const bf16x8*)&Vs[df * 16 + li][g * 8];
      O[df] = mfma16(pa, bv, O[df]);
    }
  }

  // epilogue: y = O/l, LayerNorm, +residual, store
  float rcl[4];
#pragma unroll
  for (int r = 0; r < 4; ++r) rcl[r] = 1.f / fmaxf(l_i[r], 1e-30f);
#pragma unroll
  for (int df = 0; df < 16; ++df)
#pragma unroll
    for (int r = 0; r < 4; ++r) O[df][r] *= rcl[r];

  float sm[4] = {0.f, 0.f, 0.f, 0.f};
#pragma unroll
  for (int df = 0; df < 16; ++df)
#pragma unroll
    for (int r = 0; r < 4; ++r) sm[r] += O[df][r];
  float mu_[4];
#pragma unroll
  for (int r = 0; r < 4; ++r) {
    float s = sm[r];
    s += __shfl_xor(s, 1); s += __shfl_xor(s, 2);
    s += __shfl_xor(s, 4); s += __shfl_xor(s, 8);
    mu_[r] = s * (1.f / 256.f);
  }
  float vr[4] = {0.f, 0.f, 0.f, 0.f};
#pragma unroll
  for (int df = 0; df < 16; ++df)
#pragma unroll
    for (int r = 0; r < 4; ++r) { float d = O[df][r] - mu_[r]; vr[r] += d * d; }
  float rstd[4];
#pragma unroll
  for (int r = 0; r < 4; ++r) {
    float s = vr[r];
    s += __shfl_xor(s, 1); s += __shfl_xor(s, 2);
    s += __shfl_xor(s, 4); s += __shfl_xor(s, 8);
    rstd[r] = rsqrtf(s * (1.f / 256.f) + 1e-5f);
  }
#pragma unroll
  for (int df = 0; df < 16; ++df) {
    int d = df * 16 + li;
    float gm = gs[d], bt = bs[d];
#pragma unroll
    for (int r = 0; r < 4; ++r) {
      int q = q0 + w * 16 + g * 4 + r;
      long idx = ((long)b * 1024 + q) * 256 + d;
      float o = (O[df][r] - mu_[r]) * rstd[r] * gm + bt + xres[idx];
      if (last) dout[idx] = o + future[idx];
      else { xres[idx] = o; xbout[idx] = f2bf(o); }
    }
  }
}

// ---------------- host ----------------
extern "C" void kernel_launch(void* const* d_in, const int* in_sizes, int n_in,
                              void* d_out, int out_size, void* d_ws, size_t ws_size,
                              hipStream_t stream) {
  const float* future  = (const float*)d_in[0];
  const float* history = (const float*)d_in[1];
  const float* graph   = (const float*)d_in[2];
  const void*  mask_hf = d_in[3];
  const void*  mask_fg = d_in[4];
  const float* Wq = (const float*)d_in[5];
  const float* bq = (const float*)d_in[6];
  const float* Wk = (const float*)d_in[7];
  const float* bk = (const float*)d_in[8];
  const float* Wv = (const float*)d_in[9];
  const float* bv = (const float*)d_in[10];
  const float* gamma = (const float*)d_in[11];
  const float* beta  = (const float*)d_in[12];
  float* dout = (float*)d_out;

  char* ws = (char*)d_ws;
  size_t off = 0;
  int* flag = (int*)(ws + off); off += 256;
  u16* Wt = (u16*)(ws + off);  off += (size_t)36 * 65536 * 2;   // 4.72 MB
  u16* xb = (u16*)(ws + off);  off += (size_t)16384 * 256 * 2;  // 8.39 MB
  float* x = (float*)(ws + off); off += (size_t)16384 * 256 * 4; // 16.78 MB
  u16* hb = (u16*)(ws + off);  off += (size_t)16384 * 256 * 2;
  u16* gb = (u16*)(ws + off);  off += (size_t)32768 * 256 * 2;
  u16* Qb = (u16*)(ws + off);  off += (size_t)16384 * 256 * 2;
  u16* Kb = (u16*)(ws + off);  off += (size_t)32768 * 256 * 2;
  u16* Vtb = (u16*)(ws + off); off += (size_t)32768 * 256 * 2;
  if (ws_size < off) return;  // insufficient workspace

  u16* WtQ = Wt;
  u16* WtK = Wt + (size_t)12 * 65536;
  u16* WtV = Wt + (size_t)24 * 65536;

  k_flag<<<1, 64, 0, stream>>>((const unsigned char*)mask_hf, flag);
  k_wtr<<<dim3(4, 4, 36), 256, 0, stream>>>(Wq, Wk, Wv, Wt);
  k_cvt<<<4096, 256, 0, stream>>>(future, xb, x, 4194304L);
  k_cvt<<<4096, 256, 0, stream>>>(history, hb, nullptr, 4194304L);
  k_cvt<<<8192, 256, 0, stream>>>(graph, gb, nullptr, 8388608L);

  for (int i = 0; i < 4; ++i) {
    const u16* src = (i < 2) ? hb : gb;
    int M2 = (i < 2) ? 16384 : 32768;
    int Nk = (i < 2) ? 1024 : 2048;
    const void* msk = (i < 2) ? mask_hf : mask_fg;
    k_gemm3<0><<<256, 256, 0, stream>>>(xb, WtQ + (size_t)i * 3 * 65536, bq + i * 768, Qb, 0);
    k_gemm3<0><<<M2 / 64, 256, 0, stream>>>(src, WtK + (size_t)i * 3 * 65536, bk + i * 768, Kb, 0);
    k_gemm3<1><<<M2 / 64, 256, 0, stream>>>(src, WtV + (size_t)i * 3 * 65536, bv + i * 768, Vtb, Nk);
    k_attn<<<256, 256, 0, stream>>>(Qb, Kb, Vtb, msk, flag,
                                    gamma + i * 256, beta + i * 256,
                                    x, xb, future, dout, (i == 3) ? 1 : 0, Nk);
  }
}

// Round 2
// 1033.803 us; speedup vs baseline: 1.1764x; 1.1764x over previous
//
#include <hip/hip_runtime.h>

typedef unsigned short u16;
typedef __bf16 bf16x8 __attribute__((ext_vector_type(8)));
typedef float f32x4 __attribute__((ext_vector_type(4)));

static __device__ __forceinline__ f32x4 mfma16(bf16x8 a, bf16x8 b, f32x4 c) {
  return __builtin_amdgcn_mfma_f32_16x16x32_bf16(a, b, c, 0, 0, 0);
}

static __device__ __forceinline__ u16 f2bf(float f) {
  union { float f; unsigned u; } v; v.f = f;
  unsigned r = v.u + 0x7fffu + ((v.u >> 16) & 1u);
  return (u16)(r >> 16);
}

// ---------------- mask element-size probe ----------------
__global__ void k_flag(const unsigned char* __restrict__ m, int* flag) {
  int t = threadIdx.x;  // 64 threads
  unsigned v = (unsigned)m[4*t+1] | (unsigned)m[4*t+2] | (unsigned)m[4*t+3];
  unsigned long long any = __ballot(v != 0);
  if (t == 0) *flag = (any == 0ull) ? 1 : 0;
}

// ---------------- weight transpose+convert: W[d][e] -> Wt[e][d] bf16 ----------------
__global__ __launch_bounds__(256) void k_wtr(const float* __restrict__ Wq,
                                             const float* __restrict__ Wk,
                                             const float* __restrict__ Wv,
                                             u16* __restrict__ Wt) {
  int m = blockIdx.z;
  const float* src = (m < 12) ? (Wq + (size_t)m * 65536)
                   : (m < 24) ? (Wk + (size_t)(m - 12) * 65536)
                              : (Wv + (size_t)(m - 24) * 65536);
  u16* dst = Wt + (size_t)m * 65536;
  __shared__ float T[64][65];
  int t = threadIdx.x;
  int d0 = blockIdx.x * 64, e0 = blockIdx.y * 64;
  for (int it = 0; it < 16; ++it) {
    int idx = it * 256 + t; int r = idx >> 6, c = idx & 63;
    T[r][c] = src[(size_t)(d0 + r) * 256 + e0 + c];
  }
  __syncthreads();
  for (int it = 0; it < 16; ++it) {
    int idx = it * 256 + t; int r = idx >> 6, c = idx & 63;
    dst[(size_t)(e0 + r) * 256 + d0 + c] = f2bf(T[c][r]);
  }
}

// ---------------- fp32 -> bf16 convert (+ optional fp32 copy) ----------------
__global__ __launch_bounds__(256) void k_cvt(const float* __restrict__ src,
                                             u16* __restrict__ db,
                                             float* dstf, long n) {
  long i = ((long)blockIdx.x * 256 + threadIdx.x) * 4;
  if (i >= n) return;
  float4 v = *(const float4*)(src + i);
  union { u16 u[4]; uint2 q; } o;
  o.u[0] = f2bf(v.x); o.u[1] = f2bf(v.y); o.u[2] = f2bf(v.z); o.u[3] = f2bf(v.w);
  *(uint2*)(db + i) = o.q;
  if (dstf) *(float4*)(dstf + i) = v;
}

// ---------------- fused 3-linear chain (unchanged from R1) ----------------
template<int MODE>
__global__ __launch_bounds__(256, 2) void k_gemm3(const u16* __restrict__ X,
                                                  const u16* __restrict__ Wt,
                                                  const float* __restrict__ bias,
                                                  u16* __restrict__ out, int Nk) {
  __shared__ __align__(16) u16 Xs[64][264];
  __shared__ __align__(16) u16 Ws[256][40];
  int t = threadIdx.x, lane = t & 63, w = t >> 6, g = lane >> 4, li = lane & 15;
  long row0 = (long)blockIdx.x * 64;

  for (int it = 0; it < 8; ++it) {
    int c = it * 256 + t, r = c >> 5, k8 = (c & 31) << 3;
    *(uint4*)&Xs[r][k8] = *(const uint4*)&X[(row0 + r) * 256 + k8];
  }

  for (int j = 0; j < 3; ++j) {
    f32x4 acc[4][4];
#pragma unroll
    for (int i = 0; i < 4; ++i)
#pragma unroll
      for (int jj = 0; jj < 4; ++jj) acc[i][jj] = (f32x4){0.f, 0.f, 0.f, 0.f};
    const u16* Wj = Wt + j * 65536;
    for (int kk = 0; kk < 8; ++kk) {
#pragma unroll
      for (int it = 0; it < 4; ++it) {
        int c = it * 256 + t, n = c >> 2, p = c & 3;
        *(uint4*)&Ws[n][p << 3] = *(const uint4*)&Wj[n * 256 + kk * 32 + (p << 3)];
      }
      __syncthreads();
      bf16x8 xf[4], wf[4];
#pragma unroll
      for (int f = 0; f < 4; ++f) xf[f] = *(const bf16x8*)&Xs[f * 16 + li][kk * 32 + g * 8];
#pragma unroll
      for (int f = 0; f < 4; ++f) wf[f] = *(const bf16x8*)&Ws[w * 64 + f * 16 + li][g * 8];
#pragma unroll
      for (int i = 0; i < 4; ++i)
#pragma unroll
        for (int jj = 0; jj < 4; ++jj)
          acc[i][jj] = (MODE == 0) ? mfma16(xf[i], wf[jj], acc[i][jj])
                                   : mfma16(wf[i], xf[jj], acc[i][jj]);
      __syncthreads();
    }
    if (j < 2) {
#pragma unroll
      for (int i = 0; i < 4; ++i)
#pragma unroll
        for (int jj = 0; jj < 4; ++jj)
#pragma unroll
          for (int r = 0; r < 4; ++r) {
            int R, C;
            if (MODE == 0) { R = i * 16 + g * 4 + r; C = w * 64 + jj * 16 + li; }
            else           { R = jj * 16 + li;       C = w * 64 + i * 16 + g * 4 + r; }
            Xs[R][C] = f2bf(acc[i][jj][r] + bias[j * 256 + C]);
          }
      __syncthreads();
    } else {
      if (MODE == 0) {
#pragma unroll
        for (int i = 0; i < 4; ++i)
#pragma unroll
          for (int jj = 0; jj < 4; ++jj)
#pragma unroll
            for (int r = 0; r < 4; ++r) {
              int R = i * 16 + g * 4 + r, C = w * 64 + jj * 16 + li;
              out[(row0 + R) * 256 + C] = f2bf(acc[i][jj][r] + bias[512 + C]);
            }
      } else {
        long b = row0 / Nk, rb = row0 - b * Nk;
#pragma unroll
        for (int i = 0; i < 4; ++i)
#pragma unroll
          for (int jj = 0; jj < 4; ++jj)
#pragma unroll
            for (int r = 0; r < 4; ++r) {
              int e = w * 64 + i * 16 + g * 4 + r, xr = jj * 16 + li;
              out[(b * 256 + e) * (long)Nk + rb + xr] = f2bf(acc[i][jj][r] + bias[512 + e]);
            }
      }
    }
  }
}

// ---------------- flash attention (no-max softmax) + fused LayerNorm ----------------
// Block = 32 q-rows. Wave w: qg=w>>1 (16-q group), h=w&1.
// QK: wave computes S[16q x 16k] (k-half h). PV: wave computes O[16q x 128d]
// (d-half h) over the full 32-k tile. No cross-wave O merge needed.
__global__ __launch_bounds__(256, 2) void k_attn(
    const u16* __restrict__ Qb, const u16* __restrict__ Kb, const u16* __restrict__ Vt,
    const void* __restrict__ mask, const int* __restrict__ flagp,
    const float* __restrict__ gamma, const float* __restrict__ beta,
    float* xres, u16* xbout,
    const float* __restrict__ future, float* __restrict__ dout, int last, int Nk) {
  __shared__ __align__(16) u16 Qs[32][264];
  __shared__ __align__(16) u16 Ks[32][264];
  __shared__ __align__(16) u16 Vs[256][40];
  __shared__ __align__(16) u16 Ps[2][16][40];
  __shared__ unsigned char Msk[32][32];
  __shared__ float gs[256], bs[256];
  __shared__ float Lred[2][2][16], Sred[2][2][16], Qred[2][2][16];

  int t = threadIdx.x, lane = t & 63, w = t >> 6, qg = w >> 1, h = w & 1;
  int g = lane >> 4, li = lane & 15;
  int b = blockIdx.x >> 5, q0 = (blockIdx.x & 31) << 5;
  int flag = *flagp;
  gs[t] = gamma[t]; bs[t] = beta[t];

  const u16* Qbase = Qb + ((long)b * 1024 + q0) * 256;
#pragma unroll
  for (int it = 0; it < 4; ++it) {
    int idx = it * 256 + t, r = idx >> 5, c = (idx & 31) << 3;
    *(uint4*)&Qs[r][c] = *(const uint4*)&Qbase[(long)r * 256 + c];
  }

  f32x4 O[8];
#pragma unroll
  for (int i = 0; i < 8; ++i) O[i] = (f32x4){0.f, 0.f, 0.f, 0.f};
  float l_l[4] = {0.f, 0.f, 0.f, 0.f};

  const u16* Kb0 = Kb + (long)b * Nk * 256;
  const u16* Vb0 = Vt + (long)b * 256 * (long)Nk;
  int iters = Nk >> 5;
  for (int ki = 0; ki < iters; ++ki) {
    int kb = ki << 5;
    __syncthreads();
#pragma unroll
    for (int it = 0; it < 4; ++it) {
      int idx = it * 256 + t, r = idx >> 5, c = (idx & 31) << 3;
      *(uint4*)&Ks[r][c] = *(const uint4*)&Kb0[(long)(kb + r) * 256 + c];
    }
#pragma unroll
    for (int it = 0; it < 4; ++it) {
      int idx = it * 256 + t, d = idx >> 2, p = (idx & 3) << 3;
      *(uint4*)&Vs[d][p] = *(const uint4*)&Vb0[(long)d * Nk + kb + p];
    }
    if (flag) {
      const int* mi = (const int*)mask + ((long)b * 1024 + q0) * Nk + kb;
      int q = t >> 3, k4 = (t & 7) << 2;
      int4 v = *(const int4*)&mi[(long)q * Nk + k4];
      Msk[q][k4]     = (unsigned char)(v.x != 0);
      Msk[q][k4 + 1] = (unsigned char)(v.y != 0);
      Msk[q][k4 + 2] = (unsigned char)(v.z != 0);
      Msk[q][k4 + 3] = (unsigned char)(v.w != 0);
    } else if (t < 64) {
      const unsigned char* mu = (const unsigned char*)mask + ((long)b * 1024 + q0) * Nk + kb;
      int q = t >> 1, c = (t & 1) << 4;
      *(uint4*)&Msk[q][c] = *(const uint4*)&mu[(long)q * Nk + c];
    }
    __syncthreads();

    // QK^T: S[16q x 16k], q-group qg, k-half h
    f32x4 s = (f32x4){0.f, 0.f, 0.f, 0.f};
#pragma unroll
    for (int kc = 0; kc < 8; ++kc) {
      bf16x8 a  = *(const bf16x8*)&Qs[qg * 16 + li][kc * 32 + g * 8];
      bf16x8 kf = *(const bf16x8*)&Ks[h * 16 + li][kc * 32 + g * 8];
      s = mfma16(a, kf, s);
    }
    // exp (no max subtraction), per-lane l accumulation, P -> LDS
#pragma unroll
    for (int r = 0; r < 4; ++r) {
      int qr = g * 4 + r;
      bool km = Msk[qg * 16 + qr][h * 16 + li] != 0;
      float e = km ? 0.f : __expf(s[r] * 0.0625f);
      l_l[r] += e;
      Ps[qg][qr][h * 16 + li] = f2bf(e);
    }
    __syncthreads();
    // PV: O[16q x 128d], d-half h, full 32-k tile
    bf16x8 pa = *(const bf16x8*)&Ps[qg][li][g * 8];
#pragma unroll
    for (int df = 0; df < 8; ++df) {
      bf16x8 bv = *(const bf16x8*)&Vs[h * 128 + df * 16 + li][g * 8];
      O[df] = mfma16(pa, bv, O[df]);
    }
  }

  // ---- epilogue: l reduce, y=O/l, LayerNorm, +residual ----
#pragma unroll
  for (int r = 0; r < 4; ++r) {
    float sv = l_l[r];
    sv += __shfl_xor(sv, 1); sv += __shfl_xor(sv, 2);
    sv += __shfl_xor(sv, 4); sv += __shfl_xor(sv, 8);
    if (li == 0) Lred[qg][h][g * 4 + r] = sv;
  }
  __syncthreads();
  float rl[4];
#pragma unroll
  for (int r = 0; r < 4; ++r) {
    float lt = Lred[qg][0][g * 4 + r] + Lred[qg][1][g * 4 + r];
    rl[r] = 1.f / fmaxf(lt, 1e-30f);
  }
#pragma unroll
  for (int df = 0; df < 8; ++df)
#pragma unroll
    for (int r = 0; r < 4; ++r) O[df][r] *= rl[r];

  float sm[4] = {0.f, 0.f, 0.f, 0.f}, s2[4] = {0.f, 0.f, 0.f, 0.f};
#pragma unroll
  for (int df = 0; df < 8; ++df)
#pragma unroll
    for (int r = 0; r < 4; ++r) { float y = O[df][r]; sm[r] += y; s2[r] += y * y; }
#pragma unroll
  for (int r = 0; r < 4; ++r) {
    float a = sm[r], c = s2[r];
    a += __shfl_xor(a, 1); a += __shfl_xor(a, 2);
    a += __shfl_xor(a, 4); a += __shfl_xor(a, 8);
    c += __shfl_xor(c, 1); c += __shfl_xor(c, 2);
    c += __shfl_xor(c, 4); c += __shfl_xor(c, 8);
    if (li == 0) { Sred[qg][h][g * 4 + r] = a; Qred[qg][h][g * 4 + r] = c; }
  }
  __syncthreads();
  float mu_[4], rstd[4];
#pragma unroll
  for (int r = 0; r < 4; ++r) {
    float S = Sred[qg][0][g * 4 + r] + Sred[qg][1][g * 4 + r];
    float Q2 = Qred[qg][0][g * 4 + r] + Qred[qg][1][g * 4 + r];
    float m = S * (1.f / 256.f);
    mu_[r] = m;
    float var = Q2 * (1.f / 256.f) - m * m;
    rstd[r] = rsqrtf(var + 1e-5f);
  }
#pragma unroll
  for (int df = 0; df < 8; ++df) {
    int d = h * 128 + df * 16 + li;
    float gm = gs[d], bt = bs[d];
#pragma unroll
    for (int r = 0; r < 4; ++r) {
      int q = q0 + qg * 16 + g * 4 + r;
      long idx = ((long)b * 1024 + q) * 256 + d;
      float o = (O[df][r] - mu_[r]) * rstd[r] * gm + bt + xres[idx];
      if (last) dout[idx] = o + future[idx];
      else { xres[idx] = o; xbout[idx] = f2bf(o); }
    }
  }
}

// ---------------- host ----------------
extern "C" void kernel_launch(void* const* d_in, const int* in_sizes, int n_in,
                              void* d_out, int out_size, void* d_ws, size_t ws_size,
                              hipStream_t stream) {
  const float* future  = (const float*)d_in[0];
  const float* history = (const float*)d_in[1];
  const float* graph   = (const float*)d_in[2];
  const void*  mask_hf = d_in[3];
  const void*  mask_fg = d_in[4];
  const float* Wq = (const float*)d_in[5];
  const float* bq = (const float*)d_in[6];
  const float* Wk = (const float*)d_in[7];
  const float* bk = (const float*)d_in[8];
  const float* Wv = (const float*)d_in[9];
  const float* bv = (const float*)d_in[10];
  const float* gamma = (const float*)d_in[11];
  const float* beta  = (const float*)d_in[12];
  float* dout = (float*)d_out;

  char* ws = (char*)d_ws;
  size_t off = 0;
  int* flag = (int*)(ws + off); off += 256;
  u16* Wt = (u16*)(ws + off);  off += (size_t)36 * 65536 * 2;
  u16* xb = (u16*)(ws + off);  off += (size_t)16384 * 256 * 2;
  float* x = (float*)(ws + off); off += (size_t)16384 * 256 * 4;
  u16* hb = (u16*)(ws + off);  off += (size_t)16384 * 256 * 2;
  u16* gb = (u16*)(ws + off);  off += (size_t)32768 * 256 * 2;
  u16* Qb = (u16*)(ws + off);  off += (size_t)16384 * 256 * 2;
  u16* Kb = (u16*)(ws + off);  off += (size_t)32768 * 256 * 2;
  u16* Vtb = (u16*)(ws + off); off += (size_t)32768 * 256 * 2;
  if (ws_size < off) return;

  u16* WtQ = Wt;
  u16* WtK = Wt + (size_t)12 * 65536;
  u16* WtV = Wt + (size_t)24 * 65536;

  k_flag<<<1, 64, 0, stream>>>((const unsigned char*)mask_hf, flag);
  k_wtr<<<dim3(4, 4, 36), 256, 0, stream>>>(Wq, Wk, Wv, Wt);
  k_cvt<<<4096, 256, 0, stream>>>(future, xb, x, 4194304L);
  k_cvt<<<4096, 256, 0, stream>>>(history, hb, nullptr, 4194304L);
  k_cvt<<<8192, 256, 0, stream>>>(graph, gb, nullptr, 8388608L);

  for (int i = 0; i < 4; ++i) {
    const u16* src = (i < 2) ? hb : gb;
    int M2 = (i < 2) ? 16384 : 32768;
    int Nk = (i < 2) ? 1024 : 2048;
    const void* msk = (i < 2) ? mask_hf : mask_fg;
    k_gemm3<0><<<256, 256, 0, stream>>>(xb, WtQ + (size_t)i * 3 * 65536, bq + i * 768, Qb, 0);
    k_gemm3<0><<<M2 / 64, 256, 0, stream>>>(src, WtK + (size_t)i * 3 * 65536, bk + i * 768, Kb, 0);
    k_gemm3<1><<<M2 / 64, 256, 0, stream>>>(src, WtV + (size_t)i * 3 * 65536, bv + i * 768, Vtb, Nk);
    k_attn<<<512, 256, 0, stream>>>(Qb, Kb, Vtb, msk, flag,
                                    gamma + i * 256, beta + i * 256,
                                    x, xb, future, dout, (i == 3) ? 1 : 0, Nk);
  }
}